// Round 1
// baseline (2646.911 us; speedup 1.0000x reference)
//
#include <hip/hip_runtime.h>

typedef unsigned short ushort_t;
typedef unsigned int uint_t;
typedef __attribute__((ext_vector_type(4))) float f32x4;
typedef __attribute__((ext_vector_type(8))) __bf16 bf16x8;

constexpr int BB = 32, SS = 128, EE = 512, HH = 512, VV = 32000;
constexpr int MM = BB * SS;   // 4096
constexpr int G3 = 3 * HH;    // 1536
constexpr int SCAN_WG = 16;

__device__ inline ushort_t f2b(float f) {
  union { float f; uint_t u; } v; v.f = f;
  uint_t r = v.u + 0x7fffu + ((v.u >> 16) & 1u);
  return (ushort_t)(r >> 16);
}
__device__ inline float b2f(ushort_t u) {
  union { float f; uint_t u; } v; v.u = ((uint_t)u) << 16;
  return v.f;
}

// ---------------- f32 -> bf16 converters ----------------
__global__ void cvt_bf16(const float* __restrict__ s, ushort_t* __restrict__ d, int n4) {
  int i = blockIdx.x * blockDim.x + threadIdx.x;
  if (i >= n4) return;
  float4 v = reinterpret_cast<const float4*>(s)[i];
  ushort4 o;
  o.x = f2b(v.x); o.y = f2b(v.y); o.z = f2b(v.z); o.w = f2b(v.w);
  reinterpret_cast<ushort4*>(d)[i] = o;
}

__global__ void cvt_split(const float* __restrict__ s, ushort_t* __restrict__ hi,
                          ushort_t* __restrict__ lo, int n4) {
  int i = blockIdx.x * blockDim.x + threadIdx.x;
  if (i >= n4) return;
  float4 v = reinterpret_cast<const float4*>(s)[i];
  float a[4] = {v.x, v.y, v.z, v.w};
  ushort4 oh, ol;
  ushort_t h;
  h = f2b(a[0]); oh.x = h; ol.x = f2b(a[0] - b2f(h));
  h = f2b(a[1]); oh.y = h; ol.y = f2b(a[1] - b2f(h));
  h = f2b(a[2]); oh.z = h; ol.z = f2b(a[2] - b2f(h));
  h = f2b(a[3]); oh.w = h; ol.w = f2b(a[3] - b2f(h));
  reinterpret_cast<ushort4*>(hi)[i] = oh;
  reinterpret_cast<ushort4*>(lo)[i] = ol;
}

// ---------------- bf16 B^T GEMM: C[M,N] = A[M,K] * B[N,K]^T (+bias[n]) ----------------
// 128x128 tile, 256 threads (4 waves, 2x2 wave grid of 64x64), BK=32,
// global_load_lds width-16 staging (m97 structure).
__global__ __launch_bounds__(256) void gemm_bt(
    const ushort_t* __restrict__ A, const ushort_t* __restrict__ B,
    float* __restrict__ C, const float* __restrict__ bias,
    int M, int N, int K) {
  __shared__ alignas(16) ushort_t As[128 * 32];
  __shared__ alignas(16) ushort_t Bs[128 * 32];
  const int tid = threadIdx.x;
  const int wave = tid >> 6, lane = tid & 63;
  const int l16 = lane & 15, quad = lane >> 4;
  const int m0 = blockIdx.x * 128, n0 = blockIdx.y * 128;
  const int wm = (wave & 1) * 64, wn = (wave >> 1) * 64;

  f32x4 acc[4][4] = {};
  const int cbase = wave * 64 + lane;  // chunk id, pass 0

  for (int kt = 0; kt < K; kt += 32) {
#pragma unroll
    for (int pass = 0; pass < 2; ++pass) {
      int c = cbase + pass * 256;     // 16B chunk index in tile [0,512)
      int r = c >> 2;                 // tile row
      int kc = (c & 3) * 8;           // bf16 elems into the 32-wide k slab
      const ushort_t* ga = A + (size_t)(m0 + r) * K + kt + kc;
      const ushort_t* gb = B + (size_t)(n0 + r) * K + kt + kc;
      int ldsoff = (wave * 64 + pass * 256) * 16;  // bytes, wave-uniform
      __builtin_amdgcn_global_load_lds(
          (const __attribute__((address_space(1))) void*)ga,
          (__attribute__((address_space(3))) void*)((char*)As + ldsoff), 16, 0, 0);
      __builtin_amdgcn_global_load_lds(
          (const __attribute__((address_space(1))) void*)gb,
          (__attribute__((address_space(3))) void*)((char*)Bs + ldsoff), 16, 0, 0);
    }
    __syncthreads();
    bf16x8 af[4], bf[4];
#pragma unroll
    for (int i = 0; i < 4; ++i)
      af[i] = *(const bf16x8*)&As[(wm + i * 16 + l16) * 32 + quad * 8];
#pragma unroll
    for (int j = 0; j < 4; ++j)
      bf[j] = *(const bf16x8*)&Bs[(wn + j * 16 + l16) * 32 + quad * 8];
#pragma unroll
    for (int i = 0; i < 4; ++i)
#pragma unroll
      for (int j = 0; j < 4; ++j)
        acc[i][j] = __builtin_amdgcn_mfma_f32_16x16x32_bf16(af[i], bf[j], acc[i][j], 0, 0, 0);
    __syncthreads();
  }
  // epilogue: D row = quad*4+reg, col = lane&15 (m89-verified layout)
#pragma unroll
  for (int i = 0; i < 4; ++i) {
    int row = m0 + wm + i * 16 + quad * 4;
#pragma unroll
    for (int j = 0; j < 4; ++j) {
      int col = n0 + wn + j * 16 + l16;
      float bv = bias ? bias[col] : 0.0f;
#pragma unroll
      for (int r = 0; r < 4; ++r)
        C[(size_t)(row + r) * N + col] = acc[i][j][r] + bv;
    }
  }
}

// ---------------- persistent GRU scan ----------------
// 16 WGs; WG g owns hidden columns [g*32, g*32+32). Per step: split-bf16 MFMA
// GEMM hg = h @ w_hh^T + b_hh for its 3 gate slices (r,z,n) -> LDS -> gates ->
// h_new (f32 + bf16 hi/lo) -> one device-scope barrier.
__global__ __launch_bounds__(256) void gru_scan(
    const float* __restrict__ xg,        // [4096,1536], row m=b*S+s
    const float* __restrict__ h0,        // [32,512]
    const float* __restrict__ b_hh,      // [1536]
    const ushort_t* __restrict__ whh_hi, // [1536,512]
    const ushort_t* __restrict__ whh_lo,
    float* __restrict__ hf32,            // ring [2][32*512]
    ushort_t* __restrict__ hbhi,         // ring [2][32*512]
    ushort_t* __restrict__ hblo,
    ushort_t* __restrict__ hs,           // [4096,512] bf16, row m=b*S+t
    int* __restrict__ bar) {
  const int g = blockIdx.x;
  const int tid = threadIdx.x;
  const int wave = tid >> 6, lane = tid & 63;
  const int l16 = lane & 15, quad = lane >> 4;
  __shared__ float lds_hg[3][32][33];

  const int gb = tid >> 3;          // batch row for gate phase
  const int gjj = (tid & 7) * 4;    // local col (x4)
  const int gj = g * 32 + gjj;      // global hidden col

  for (int t = 0; t < SS; ++t) {
    const int p = t & 1;
    const ushort_t* hhi = hbhi + p * (BB * HH);
    const ushort_t* hlo = hblo + p * (BB * HH);
    // ---- GEMM phase: 12 (mt,sec,nc) subtile tasks over 4 waves ----
#pragma unroll
    for (int i = 0; i < 3; ++i) {
      int idx = wave + 4 * i;        // 0..11
      int mt = idx & 1;
      int rest = idx >> 1;           // 0..5
      int sec = rest % 3, nc = rest / 3;
      int n0 = sec * 512 + g * 32 + nc * 16;
      const ushort_t* ar  = hhi + (mt * 16 + l16) * HH + quad * 8;
      const ushort_t* arl = hlo + (mt * 16 + l16) * HH + quad * 8;
      const ushort_t* br  = whh_hi + (size_t)(n0 + l16) * HH + quad * 8;
      const ushort_t* brl = whh_lo + (size_t)(n0 + l16) * HH + quad * 8;
      f32x4 acc = {0.f, 0.f, 0.f, 0.f};
      for (int kk = 0; kk < HH; kk += 32) {
        bf16x8 ah = *(const bf16x8*)(ar + kk);
        bf16x8 al = *(const bf16x8*)(arl + kk);
        bf16x8 bh = *(const bf16x8*)(br + kk);
        bf16x8 bl = *(const bf16x8*)(brl + kk);
        acc = __builtin_amdgcn_mfma_f32_16x16x32_bf16(ah, bh, acc, 0, 0, 0);
        acc = __builtin_amdgcn_mfma_f32_16x16x32_bf16(ah, bl, acc, 0, 0, 0);
        acc = __builtin_amdgcn_mfma_f32_16x16x32_bf16(al, bh, acc, 0, 0, 0);
      }
      float bias = b_hh[n0 + l16];
#pragma unroll
      for (int r = 0; r < 4; ++r)
        lds_hg[sec][mt * 16 + quad * 4 + r][nc * 16 + l16] = acc[r] + bias;
    }
    __syncthreads();
    // ---- gate phase: each thread does 4 (b, j) outputs ----
    {
      const float* hcf = hf32 + p * (BB * HH);
      int mrow = gb * SS + t;
      const float* xgp = xg + (size_t)mrow * G3 + gj;
      float4 xr = *(const float4*)(xgp);
      float4 xz = *(const float4*)(xgp + 512);
      float4 xn = *(const float4*)(xgp + 1024);
      float4 hv = (t == 0) ? *(const float4*)(h0 + gb * HH + gj)
                           : *(const float4*)(hcf + gb * HH + gj);
      float xra[4] = {xr.x, xr.y, xr.z, xr.w};
      float xza[4] = {xz.x, xz.y, xz.z, xz.w};
      float xna[4] = {xn.x, xn.y, xn.z, xn.w};
      float hva[4] = {hv.x, hv.y, hv.z, hv.w};
      float outv[4]; ushort_t ohi[4], olo[4];
#pragma unroll
      for (int q = 0; q < 4; ++q) {
        float hr = lds_hg[0][gb][gjj + q];
        float hz = lds_hg[1][gb][gjj + q];
        float hn = lds_hg[2][gb][gjj + q];
        float r = 1.f / (1.f + __expf(-(xra[q] + hr)));
        float z = 1.f / (1.f + __expf(-(xza[q] + hz)));
        float pre = xna[q] + r * hn;
        pre = fminf(fmaxf(pre, -15.f), 15.f);
        float e = __expf(2.f * pre);
        float n = (e - 1.f) / (e + 1.f);
        float hnew = (1.f - z) * n + z * hva[q];
        outv[q] = hnew;
        ushort_t hb = f2b(hnew);
        ohi[q] = hb;
        olo[q] = f2b(hnew - b2f(hb));
      }
      float* hf_next = hf32 + (p ^ 1) * (BB * HH);
      ushort_t* hhi_n = hbhi + (p ^ 1) * (BB * HH);
      ushort_t* hlo_n = hblo + (p ^ 1) * (BB * HH);
      *(float4*)(hf_next + gb * HH + gj) = make_float4(outv[0], outv[1], outv[2], outv[3]);
      ushort4 uh; uh.x = ohi[0]; uh.y = ohi[1]; uh.z = ohi[2]; uh.w = ohi[3];
      ushort4 ul; ul.x = olo[0]; ul.y = olo[1]; ul.z = olo[2]; ul.w = olo[3];
      *(ushort4*)(hhi_n + gb * HH + gj) = uh;
      *(ushort4*)(hlo_n + gb * HH + gj) = ul;
      *(ushort4*)(hs + (size_t)mrow * HH + gj) = uh;
    }
    // ---- grid barrier (device-scope; 16 co-resident WGs) ----
    __syncthreads();                 // drains vmcnt before fence/arrive
    if (tid == 0) {
      __threadfence();               // release: L2 writeback, agent scope
      atomicAdd(bar, 1);
      int target = (t + 1) * SCAN_WG;
      while (atomicAdd(bar, 0) < target) __builtin_amdgcn_s_sleep(2);
      __threadfence();               // acquire: invalidate L1/L2
    }
    __syncthreads();
  }
}

extern "C" void kernel_launch(void* const* d_in, const int* in_sizes, int n_in,
                              void* d_out, int out_size, void* d_ws, size_t ws_size,
                              hipStream_t stream) {
  (void)in_sizes; (void)n_in; (void)out_size; (void)ws_size;
  const float* embed  = (const float*)d_in[0];  // [B,S,E]
  const float* hidden = (const float*)d_in[1];  // [1,B,H]
  const float* w_ih   = (const float*)d_in[2];  // [3H,E]
  const float* w_hh   = (const float*)d_in[3];  // [3H,H]
  const float* b_ih   = (const float*)d_in[4];  // [3H]
  const float* b_hh   = (const float*)d_in[5];  // [3H]
  const float* w_out  = (const float*)d_in[6];  // [V,H]
  float* out = (float*)d_out;

  char* ws = (char*)d_ws;
  size_t off = 0;
  auto alloc = [&](size_t bytes) {
    void* p = ws + off;
    off += (bytes + 255) & ~(size_t)255;
    return p;
  };
  float*    xg     = (float*)   alloc((size_t)MM * G3 * 4);   // 25.2 MB
  ushort_t* emb16  = (ushort_t*)alloc((size_t)MM * EE * 2);   // 4.2 MB
  ushort_t* wih16  = (ushort_t*)alloc((size_t)G3 * EE * 2);   // 1.5 MB
  ushort_t* whh_hi = (ushort_t*)alloc((size_t)G3 * HH * 2);   // 1.5 MB
  ushort_t* whh_lo = (ushort_t*)alloc((size_t)G3 * HH * 2);   // 1.5 MB
  ushort_t* wout16 = (ushort_t*)alloc((size_t)VV * HH * 2);   // 32.8 MB
  ushort_t* hs16   = (ushort_t*)alloc((size_t)MM * HH * 2);   // 4.2 MB
  float*    hf     = (float*)   alloc((size_t)2 * BB * HH * 4);
  ushort_t* hbhi   = (ushort_t*)alloc((size_t)2 * BB * HH * 2);
  ushort_t* hblo   = (ushort_t*)alloc((size_t)2 * BB * HH * 2);
  int*      bar    = (int*)     alloc(256);

  hipMemsetAsync(bar, 0, 256, stream);

  cvt_bf16 <<<2048,  256, 0, stream>>>(embed, emb16, MM * EE / 4);
  cvt_bf16 <<<768,   256, 0, stream>>>(w_ih, wih16, G3 * EE / 4);
  cvt_split<<<768,   256, 0, stream>>>(w_hh, whh_hi, whh_lo, G3 * HH / 4);
  cvt_bf16 <<<16000, 256, 0, stream>>>(w_out, wout16, VV * HH / 4);
  cvt_split<<<16,    256, 0, stream>>>(hidden, hbhi, hblo, BB * HH / 4);

  // x-gates: xg[m, g] = embed[m,:] . w_ih[g,:] + b_ih[g]
  gemm_bt<<<dim3(MM / 128, G3 / 128), 256, 0, stream>>>(emb16, wih16, xg, b_ih, MM, G3, EE);

  gru_scan<<<SCAN_WG, 256, 0, stream>>>(xg, hidden, b_hh, whh_hi, whh_lo,
                                        hf, hbhi, hblo, hs16, bar);

  // projection: out[m, v] = hs[m,:] . w_out[v,:]  (m = b*S+s matches d_out layout)
  gemm_bt<<<dim3(MM / 128, VV / 128), 256, 0, stream>>>(hs16, wout16, out, nullptr, MM, VV, HH);
}